// Round 5
// baseline (137.388 us; speedup 1.0000x reference)
//
#include <hip/hip_runtime.h>

typedef unsigned long long u64;
typedef unsigned short u16;
typedef __attribute__((ext_vector_type(8))) short short8;   // 8 bf16 (4 VGPRs)
typedef __attribute__((ext_vector_type(4))) float f32x4;

#define C_DIM 128

__device__ inline u16 bf16_rn(float f) {
    unsigned u = __float_as_uint(f);
    u += 0x7FFF + ((u >> 16) & 1);          // round-to-nearest-even
    return (u16)(u >> 16);
}
__device__ inline float bf16_tof(u16 h) { return __uint_as_float(((unsigned)h) << 16); }

// k0: prep — edge bitmap + PACKED per-row neighbor list (dedup via atomicOr
// old-value), bf16 hi/lo split of x (float4) and Wq/Wk/Wv/Wo (float4).
// grid = 512 blocks x 256 threads (covers E = xq = 131072).
__global__ __launch_bounds__(256) void prep_kernel(
    const int* __restrict__ ei, int E, u64* __restrict__ bm, int wpr,
    int* __restrict__ deg, u16* __restrict__ lists,
    const float* __restrict__ x, u16* __restrict__ xh, u16* __restrict__ xl, int xq,
    const float* __restrict__ wq, const float* __restrict__ wk,
    const float* __restrict__ wv, const float* __restrict__ wo,
    u16* __restrict__ wH, u16* __restrict__ wL)
{
    int tid = blockIdx.x * 256 + threadIdx.x;
    // ---- edge scatter: bitmap dedup + packed list build ----
    if (tid < E) {
        int r = ei[tid], c = ei[E + tid];
        u64 mask = 1ull << (c & 63);
        u64 old = atomicOr(&bm[(size_t)r * wpr + (c >> 6)], mask);
        if (!(old & mask)) {                       // first time this edge appears
            int slot = atomicAdd(&deg[r], 1);
            if (slot < 64) lists[(size_t)r * 64 + slot] = (u16)c;
        }
    }
    // ---- W hi/lo bf16 split, float4-vectorized: 4 mats x 4096 float4s ----
    if (tid < 4 * 4096) {
        int s = tid >> 12, i4 = tid & 4095;
        const float* W = (s == 0) ? wq : (s == 1) ? wk : (s == 2) ? wv : wo;
        float4 f = ((const float4*)W)[i4];
        ushort4 h, l;
        h.x = bf16_rn(f.x); l.x = bf16_rn(f.x - bf16_tof(h.x));
        h.y = bf16_rn(f.y); l.y = bf16_rn(f.y - bf16_tof(h.y));
        h.z = bf16_rn(f.z); l.z = bf16_rn(f.z - bf16_tof(h.z));
        h.w = bf16_rn(f.w); l.w = bf16_rn(f.w - bf16_tof(h.w));
        ((ushort4*)(wH + (size_t)s * 16384))[i4] = h;
        ((ushort4*)(wL + (size_t)s * 16384))[i4] = l;
    }
    // ---- x hi/lo bf16 split, 4 elems/thread ----
    if (tid < xq) {
        float4 xv = ((const float4*)x)[tid];
        ushort4 h, l;
        h.x = bf16_rn(xv.x); l.x = bf16_rn(xv.x - bf16_tof(h.x));
        h.y = bf16_rn(xv.y); l.y = bf16_rn(xv.y - bf16_tof(h.y));
        h.z = bf16_rn(xv.z); l.z = bf16_rn(xv.z - bf16_tof(h.z));
        h.w = bf16_rn(xv.w); l.w = bf16_rn(xv.w - bf16_tof(h.w));
        ((ushort4*)xh)[tid] = h;
        ((ushort4*)xl)[tid] = l;
    }
}

// k1: qkv = x @ W^T + b via 3-term bf16-split MFMA. 32 rows/block (2 row-tiles
// sharing B-fragments -> half the weight L2 traffic of 16-row blocks).
// grid = 3*(N/32) = 384 blocks x 256 threads. q gets 1/sqrt(32) folded in.
// C/D: col = lane&15, row = (lane>>4)*4 + reg  [m89-verified].
__global__ __launch_bounds__(256) void qkv_mfma_kernel(
    const u16* __restrict__ xh, const u16* __restrict__ xl,
    const u16* __restrict__ wH, const u16* __restrict__ wL,
    const float* __restrict__ bq, const float* __restrict__ bk, const float* __restrict__ bv,
    float* __restrict__ qo, float* __restrict__ ko, float* __restrict__ vo, int nrg)
{
    int bid = blockIdx.x;
    int s = bid / nrg;          // 0..2 (q/k/v)
    int rg = bid % nrg;
    int r0 = rg * 32;
    int w  = threadIdx.x >> 6;  // wave 0..3
    int l  = threadIdx.x & 63;
    int j0 = w * 32;
    int lr = l & 15;
    int kg = l >> 4;

    const u16* a0h = xh + (size_t)(r0 + lr) * C_DIM + kg * 8;
    const u16* a0l = xl + (size_t)(r0 + lr) * C_DIM + kg * 8;
    const u16* a1h = a0h + 16 * C_DIM;
    const u16* a1l = a0l + 16 * C_DIM;
    const u16* w0h = wH + (size_t)s * 16384 + (size_t)(j0 + lr) * C_DIM + kg * 8;
    const u16* w0l = wL + (size_t)s * 16384 + (size_t)(j0 + lr) * C_DIM + kg * 8;
    const u16* w1h = w0h + 16 * C_DIM;
    const u16* w1l = w0l + 16 * C_DIM;
    const float* B = (s == 0) ? bq : (s == 1) ? bk : bv;
    float*       O = (s == 0) ? qo : (s == 1) ? ko : vo;
    float fin = (s == 0) ? 0.17677669529663687f : 1.0f;   // fold q scale

    float b0 = B[j0 + lr], b1 = B[j0 + 16 + lr];
    f32x4 acc00 = {b0, b0, b0, b0};   // row-tile 0, col-tile 0
    f32x4 acc01 = {b1, b1, b1, b1};   // row-tile 0, col-tile 1
    f32x4 acc10 = {b0, b0, b0, b0};   // row-tile 1, col-tile 0
    f32x4 acc11 = {b1, b1, b1, b1};

    #pragma unroll
    for (int kk = 0; kk < C_DIM; kk += 32) {
        short8 ah0 = *(const short8*)(a0h + kk);
        short8 al0 = *(const short8*)(a0l + kk);
        short8 ah1 = *(const short8*)(a1h + kk);
        short8 al1 = *(const short8*)(a1l + kk);
        short8 bh0 = *(const short8*)(w0h + kk);
        short8 bl0 = *(const short8*)(w0l + kk);
        short8 bh1 = *(const short8*)(w1h + kk);
        short8 bl1 = *(const short8*)(w1l + kk);
        acc00 = __builtin_amdgcn_mfma_f32_16x16x32_bf16(ah0, bh0, acc00, 0, 0, 0);
        acc00 = __builtin_amdgcn_mfma_f32_16x16x32_bf16(ah0, bl0, acc00, 0, 0, 0);
        acc00 = __builtin_amdgcn_mfma_f32_16x16x32_bf16(al0, bh0, acc00, 0, 0, 0);
        acc01 = __builtin_amdgcn_mfma_f32_16x16x32_bf16(ah0, bh1, acc01, 0, 0, 0);
        acc01 = __builtin_amdgcn_mfma_f32_16x16x32_bf16(ah0, bl1, acc01, 0, 0, 0);
        acc01 = __builtin_amdgcn_mfma_f32_16x16x32_bf16(al0, bh1, acc01, 0, 0, 0);
        acc10 = __builtin_amdgcn_mfma_f32_16x16x32_bf16(ah1, bh0, acc10, 0, 0, 0);
        acc10 = __builtin_amdgcn_mfma_f32_16x16x32_bf16(ah1, bl0, acc10, 0, 0, 0);
        acc10 = __builtin_amdgcn_mfma_f32_16x16x32_bf16(al1, bh0, acc10, 0, 0, 0);
        acc11 = __builtin_amdgcn_mfma_f32_16x16x32_bf16(ah1, bh1, acc11, 0, 0, 0);
        acc11 = __builtin_amdgcn_mfma_f32_16x16x32_bf16(ah1, bl1, acc11, 0, 0, 0);
        acc11 = __builtin_amdgcn_mfma_f32_16x16x32_bf16(al1, bh1, acc11, 0, 0, 0);
    }
    #pragma unroll
    for (int i = 0; i < 4; ++i) {
        size_t ro0 = (size_t)(r0 + kg * 4 + i) * C_DIM;
        size_t ro1 = (size_t)(r0 + 16 + kg * 4 + i) * C_DIM;
        O[ro0 + j0 + lr]      = acc00[i] * fin;
        O[ro0 + j0 + 16 + lr] = acc01[i] * fin;
        O[ro1 + j0 + lr]      = acc10[i] * fin;
        O[ro1 + j0 + 16 + lr] = acc11[i] * fin;
    }
}

// k2: attention. wave = row, 8 rows/block, 512 blocks x 512 threads.
// ZERO LDS, zero barriers: packed neighbor list prebuilt by prep; each lane
// holds one list entry, broadcast per-neighbor via __shfl(entry, literal) ->
// v_readlane -> SGPR-base coalesced row gathers. Scores in registers (slot
// j>>4, lane j&15 of 16-lane head-group). Output: ao * sinv as bf16 hi/lo.
__global__ __launch_bounds__(512, 4) void attn_kernel(
    const float* __restrict__ q, const float* __restrict__ k,
    const float* __restrict__ v, const int* __restrict__ deg,
    const u16* __restrict__ lists,
    u16* __restrict__ aoh, u16* __restrict__ aol)
{
    int t = threadIdx.x;
    int wave = t >> 6, lane = t & 63;
    int n = blockIdx.x * 8 + wave;    // this wave's row

    int cnt = deg[n];                 // uniform address -> broadcast load
    if (cnt > 64) cnt = 64;
    cnt = __builtin_amdgcn_readfirstlane(cnt);
    int le = lists[(size_t)n * 64 + lane];   // lane's list entry (coalesced 128B)

    int g = lane >> 4;                // head of this lane's dims (2l,2l+1)
    float2 qf = *(const float2*)(q + (size_t)n * C_DIM + 2 * lane);  // scale pre-folded

    float sc0 = -1e30f, sc1 = -1e30f, sc2 = -1e30f, sc3 = -1e30f;
    float2 buf[32];                   // shared k-chunk / v-chunk staging

    // ---- scoring chunk 0 (j = 0..31) ----
    {
        int top = cnt < 32 ? cnt : 32;
        #pragma unroll
        for (int u = 0; u < 32; ++u)
            if (u < top) {
                int m = __shfl(le, u);     // readlane -> SGPR
                buf[u] = *(const float2*)(k + (size_t)m * C_DIM + 2 * lane);
            }
        #pragma unroll
        for (int u = 0; u < 32; ++u)
            if (u < top) {
                float s = qf.x * buf[u].x + qf.y * buf[u].y;
                s += __shfl_xor(s, 1); s += __shfl_xor(s, 2);
                s += __shfl_xor(s, 4); s += __shfl_xor(s, 8);
                if ((lane & 15) == (u & 15)) { if (u < 16) sc0 = s; else sc1 = s; }
            }
    }
    // ---- scoring chunk 1 (j = 32..63) ----
    if (cnt > 32) {
        #pragma unroll
        for (int u = 0; u < 32; ++u)
            if (32 + u < cnt) {
                int m = __shfl(le, 32 + u);
                buf[u] = *(const float2*)(k + (size_t)m * C_DIM + 2 * lane);
            }
        #pragma unroll
        for (int u = 0; u < 32; ++u)
            if (32 + u < cnt) {
                float s = qf.x * buf[u].x + qf.y * buf[u].y;
                s += __shfl_xor(s, 1); s += __shfl_xor(s, 2);
                s += __shfl_xor(s, 4); s += __shfl_xor(s, 8);
                if ((lane & 15) == (u & 15)) { if (u < 16) sc2 = s; else sc3 = s; }
            }
    }
    // ---- prefetch v chunk 0 (latency hides under softmax) ----
    {
        int top = cnt < 32 ? cnt : 32;
        #pragma unroll
        for (int u = 0; u < 32; ++u)
            if (u < top) {
                int m = __shfl(le, u);
                buf[u] = *(const float2*)(v + (size_t)m * C_DIM + 2 * lane);
            }
    }
    // ---- softmax on register slots (16-lane group = head g) ----
    float mx = fmaxf(fmaxf(sc0, sc1), fmaxf(sc2, sc3));
    mx = fmaxf(mx, __shfl_xor(mx, 1)); mx = fmaxf(mx, __shfl_xor(mx, 2));
    mx = fmaxf(mx, __shfl_xor(mx, 4)); mx = fmaxf(mx, __shfl_xor(mx, 8));
    float e0 = __expf(sc0 - mx), e1 = __expf(sc1 - mx);
    float e2 = __expf(sc2 - mx), e3 = __expf(sc3 - mx);   // invalid slots -> 0
    float sum = (e0 + e1) + (e2 + e3);
    sum += __shfl_xor(sum, 1); sum += __shfl_xor(sum, 2);
    sum += __shfl_xor(sum, 4); sum += __shfl_xor(sum, 8);
    float sinv = 1.0f / sum;          // >=1 neighbor (self-loop)

    // ---- PV chunk 0: e_j broadcast from lane (g<<4)|(j&15), slot j>>4 ----
    float2 acc = {0.f, 0.f};
    {
        int top = cnt < 32 ? cnt : 32;
        #pragma unroll
        for (int u = 0; u < 32; ++u)
            if (u < top) {
                float e = __shfl((u < 16) ? e0 : e1, (g << 4) | (u & 15));
                acc.x += e * buf[u].x;
                acc.y += e * buf[u].y;
            }
    }
    // ---- v chunk 1 + PV ----
    if (cnt > 32) {
        #pragma unroll
        for (int u = 0; u < 32; ++u)
            if (32 + u < cnt) {
                int m = __shfl(le, 32 + u);
                buf[u] = *(const float2*)(v + (size_t)m * C_DIM + 2 * lane);
            }
        #pragma unroll
        for (int u = 0; u < 32; ++u)
            if (32 + u < cnt) {
                float e = __shfl((u < 16) ? e2 : e3, (g << 4) | (u & 15));
                acc.x += e * buf[u].x;
                acc.y += e * buf[u].y;
            }
    }
    // ---- store ao as bf16 hi/lo split ----
    float f0 = acc.x * sinv, f1 = acc.y * sinv;
    ushort2 ho, lo;
    ho.x = bf16_rn(f0); lo.x = bf16_rn(f0 - bf16_tof(ho.x));
    ho.y = bf16_rn(f1); lo.y = bf16_rn(f1 - bf16_tof(ho.y));
    *(ushort2*)(aoh + (size_t)n * C_DIM + 2 * lane) = ho;
    *(ushort2*)(aol + (size_t)n * C_DIM + 2 * lane) = lo;
}

// k3: y = ao @ wo^T + bo + x, then LayerNorm. 32 rows/block (2 row-tiles
// sharing B-fragments), 128 blocks x 256 threads; wo pre-split by prep.
__global__ __launch_bounds__(256) void oln_kernel(
    const u16* __restrict__ aoh, const u16* __restrict__ aol,
    const u16* __restrict__ woh, const u16* __restrict__ wol,
    const float* __restrict__ bo, const float* __restrict__ x,
    const float* __restrict__ gamma, const float* __restrict__ beta,
    float* __restrict__ out)
{
    __shared__ float ys[32 * 132];    // padded leading dim
    int r0 = blockIdx.x * 32;
    int w  = threadIdx.x >> 6;
    int l  = threadIdx.x & 63;
    int j0 = w * 32;
    int lr = l & 15;
    int kg = l >> 4;

    const u16* a0h = aoh + (size_t)(r0 + lr) * C_DIM + kg * 8;
    const u16* a0l = aol + (size_t)(r0 + lr) * C_DIM + kg * 8;
    const u16* a1h = a0h + 16 * C_DIM;
    const u16* a1l = a0l + 16 * C_DIM;
    const u16* w0h = woh + (size_t)(j0 + lr) * C_DIM + kg * 8;
    const u16* w0l = wol + (size_t)(j0 + lr) * C_DIM + kg * 8;
    const u16* w1h = w0h + 16 * C_DIM;
    const u16* w1l = w0l + 16 * C_DIM;

    float b0 = bo[j0 + lr], b1 = bo[j0 + 16 + lr];
    f32x4 acc00 = {b0, b0, b0, b0};
    f32x4 acc01 = {b1, b1, b1, b1};
    f32x4 acc10 = {b0, b0, b0, b0};
    f32x4 acc11 = {b1, b1, b1, b1};

    #pragma unroll
    for (int kk = 0; kk < C_DIM; kk += 32) {
        short8 ah0 = *(const short8*)(a0h + kk);
        short8 al0 = *(const short8*)(a0l + kk);
        short8 ah1 = *(const short8*)(a1h + kk);
        short8 al1 = *(const short8*)(a1l + kk);
        short8 bh0 = *(const short8*)(w0h + kk);
        short8 bl0 = *(const short8*)(w0l + kk);
        short8 bh1 = *(const short8*)(w1h + kk);
        short8 bl1 = *(const short8*)(w1l + kk);
        acc00 = __builtin_amdgcn_mfma_f32_16x16x32_bf16(ah0, bh0, acc00, 0, 0, 0);
        acc00 = __builtin_amdgcn_mfma_f32_16x16x32_bf16(ah0, bl0, acc00, 0, 0, 0);
        acc00 = __builtin_amdgcn_mfma_f32_16x16x32_bf16(al0, bh0, acc00, 0, 0, 0);
        acc01 = __builtin_amdgcn_mfma_f32_16x16x32_bf16(ah0, bh1, acc01, 0, 0, 0);
        acc01 = __builtin_amdgcn_mfma_f32_16x16x32_bf16(ah0, bl1, acc01, 0, 0, 0);
        acc01 = __builtin_amdgcn_mfma_f32_16x16x32_bf16(al0, bh1, acc01, 0, 0, 0);
        acc10 = __builtin_amdgcn_mfma_f32_16x16x32_bf16(ah1, bh0, acc10, 0, 0, 0);
        acc10 = __builtin_amdgcn_mfma_f32_16x16x32_bf16(ah1, bl0, acc10, 0, 0, 0);
        acc10 = __builtin_amdgcn_mfma_f32_16x16x32_bf16(al1, bh0, acc10, 0, 0, 0);
        acc11 = __builtin_amdgcn_mfma_f32_16x16x32_bf16(ah1, bh1, acc11, 0, 0, 0);
        acc11 = __builtin_amdgcn_mfma_f32_16x16x32_bf16(ah1, bl1, acc11, 0, 0, 0);
        acc11 = __builtin_amdgcn_mfma_f32_16x16x32_bf16(al1, bh1, acc11, 0, 0, 0);
    }
    // ---- residual into LDS; rows rt*16 + kg*4 + i (all 32 real) ----
    #pragma unroll
    for (int i = 0; i < 4; ++i) {
        int rr0 = kg * 4 + i;
        int rr1 = 16 + kg * 4 + i;
        ys[rr0 * 132 + j0 + lr]      = acc00[i] + x[(size_t)(r0 + rr0) * C_DIM + j0 + lr];
        ys[rr0 * 132 + j0 + 16 + lr] = acc01[i] + x[(size_t)(r0 + rr0) * C_DIM + j0 + 16 + lr];
        ys[rr1 * 132 + j0 + lr]      = acc10[i] + x[(size_t)(r0 + rr1) * C_DIM + j0 + lr];
        ys[rr1 * 132 + j0 + 16 + lr] = acc11[i] + x[(size_t)(r0 + rr1) * C_DIM + j0 + 16 + lr];
    }
    __syncthreads();
    // ---- LN: 8 threads per row, 16 cols each (256 threads = 32 rows) ----
    {
        int rr = threadIdx.x >> 3;
        int c0 = (threadIdx.x & 7) * 16;
        float yv[16];
        float s = 0.f, s2 = 0.f;
        #pragma unroll
        for (int u = 0; u < 16; ++u) {
            yv[u] = ys[rr * 132 + c0 + u];
            s += yv[u]; s2 += yv[u] * yv[u];
        }
        #pragma unroll
        for (int off = 4; off; off >>= 1) {
            s  += __shfl_xor(s, off);
            s2 += __shfl_xor(s2, off);
        }
        float mu = s * (1.0f / 128.0f);
        float var = s2 * (1.0f / 128.0f) - mu * mu;
        float rstd = rsqrtf(var + 1e-5f);
        size_t o = (size_t)(r0 + rr) * C_DIM + c0;
        #pragma unroll
        for (int u = 0; u < 16; ++u)
            out[o + u] = (yv[u] - mu) * rstd * gamma[c0 + u] + beta[c0 + u];
    }
}

extern "C" void kernel_launch(void* const* d_in, const int* in_sizes, int n_in,
                              void* d_out, int out_size, void* d_ws, size_t ws_size,
                              hipStream_t stream)
{
    const float* x     = (const float*)d_in[0];
    const int*   ei    = (const int*)d_in[1];
    const float* wq    = (const float*)d_in[2];
    const float* bq    = (const float*)d_in[3];
    const float* wk    = (const float*)d_in[4];
    const float* bk    = (const float*)d_in[5];
    const float* wv    = (const float*)d_in[6];
    const float* bv    = (const float*)d_in[7];
    const float* wo    = (const float*)d_in[8];
    const float* bo    = (const float*)d_in[9];
    const float* gamma = (const float*)d_in[10];
    const float* beta  = (const float*)d_in[11];
    float* out = (float*)d_out;

    int N = in_sizes[0] / C_DIM;   // 4096
    int E = in_sizes[1] / 2;       // 131072
    int wpr = N >> 6;              // u64 words per bitmap row (64)

    size_t MB = 1 << 20;
    char* base = (char*)d_ws;
    float* q     = (float*)(base + 0 * MB);            // 2 MiB
    float* k     = (float*)(base + 2 * MB);            // 2 MiB
    float* v     = (float*)(base + 4 * MB);            // 2 MiB
    u64*   bm    = (u64*)(base + 6 * MB);              // 2 MiB (N*N bits)
    int*   deg   = (int*)(base + 8 * MB);              // 16 KiB (zeroed with bm)
    u16*   lists = (u16*)(base + 8 * MB + 64 * 1024);  // 512 KiB (N*64 u16)
    u16*   xh    = (u16*)(base + 9 * MB);              // 1 MiB
    u16*   xl    = (u16*)(base + 10 * MB);             // 1 MiB
    u16*   wH    = (u16*)(base + 11 * MB);             // 128 KiB (q,k,v,o)
    u16*   wL    = (u16*)(base + 11 * MB + 256 * 1024);// 128 KiB
    u16*   aoh   = (u16*)(base + 12 * MB);             // 1 MiB
    u16*   aol   = (u16*)(base + 13 * MB);             // 1 MiB

    // one memset covers bm (2 MiB) + deg (16 KiB), contiguous
    hipMemsetAsync(bm, 0, 2 * MB + (size_t)N * sizeof(int), stream);

    int xq = N * C_DIM / 4;                  // 131072 float4s
    int nwork = (E > xq) ? E : xq;
    prep_kernel<<<(nwork + 255) / 256, 256, 0, stream>>>(
        ei, E, bm, wpr, deg, lists, x, xh, xl, xq, wq, wk, wv, wo, wH, wL);

    int nrg = N / 32;                        // 128 row-groups
    qkv_mfma_kernel<<<3 * nrg, 256, 0, stream>>>(
        xh, xl, wH, wL, bq, bk, bv, q, k, v, nrg);

    attn_kernel<<<N / 8, 512, 0, stream>>>(q, k, v, deg, lists, aoh, aol);

    oln_kernel<<<N / 32, 256, 0, stream>>>(
        aoh, aol, wH + 3 * C_DIM * C_DIM, wL + 3 * C_DIM * C_DIM,
        bo, x, gamma, beta, out);
}

// Round 6
// 123.646 us; speedup vs baseline: 1.1111x; 1.1111x over previous
//
#include <hip/hip_runtime.h>

typedef unsigned long long u64;
typedef unsigned short u16;
typedef __attribute__((ext_vector_type(8))) short short8;   // 8 bf16 (4 VGPRs)
typedef __attribute__((ext_vector_type(4))) float f32x4;

#define C_DIM 128

__device__ inline u16 bf16_rn(float f) {
    unsigned u = __float_as_uint(f);
    u += 0x7FFF + ((u >> 16) & 1);          // round-to-nearest-even
    return (u16)(u >> 16);
}
__device__ inline float bf16_tof(u16 h) { return __uint_as_float(((unsigned)h) << 16); }

// k0: prep — edge bitmap (fire-and-forget atomicOr), bf16 hi/lo split of x
// and Wq/Wk/Wv/Wo (both float4-vectorized). grid = 512 blocks x 256 threads.
__global__ __launch_bounds__(256) void prep_kernel(
    const int* __restrict__ ei, int E, u64* __restrict__ bm, int wpr,
    const float* __restrict__ x, u16* __restrict__ xh, u16* __restrict__ xl, int xq,
    const float* __restrict__ wq, const float* __restrict__ wk,
    const float* __restrict__ wv, const float* __restrict__ wo,
    u16* __restrict__ wH, u16* __restrict__ wL)
{
    int tid = blockIdx.x * 256 + threadIdx.x;
    // ---- edge bitmap (dedup via bits; reference mask is idempotent) ----
    if (tid < E) {
        int r = ei[tid], c = ei[E + tid];
        atomicOr(&bm[(size_t)r * wpr + (c >> 6)], 1ull << (c & 63));
    }
    // ---- W hi/lo bf16 split, float4-vectorized: 4 mats x 4096 float4s ----
    if (tid < 4 * 4096) {
        int s = tid >> 12, i4 = tid & 4095;
        const float* W = (s == 0) ? wq : (s == 1) ? wk : (s == 2) ? wv : wo;
        float4 f = ((const float4*)W)[i4];
        ushort4 h, l;
        h.x = bf16_rn(f.x); l.x = bf16_rn(f.x - bf16_tof(h.x));
        h.y = bf16_rn(f.y); l.y = bf16_rn(f.y - bf16_tof(h.y));
        h.z = bf16_rn(f.z); l.z = bf16_rn(f.z - bf16_tof(h.z));
        h.w = bf16_rn(f.w); l.w = bf16_rn(f.w - bf16_tof(h.w));
        ((ushort4*)(wH + (size_t)s * 16384))[i4] = h;
        ((ushort4*)(wL + (size_t)s * 16384))[i4] = l;
    }
    // ---- x hi/lo bf16 split, 4 elems/thread ----
    if (tid < xq) {
        float4 xv = ((const float4*)x)[tid];
        ushort4 h, l;
        h.x = bf16_rn(xv.x); l.x = bf16_rn(xv.x - bf16_tof(h.x));
        h.y = bf16_rn(xv.y); l.y = bf16_rn(xv.y - bf16_tof(h.y));
        h.z = bf16_rn(xv.z); l.z = bf16_rn(xv.z - bf16_tof(h.z));
        h.w = bf16_rn(xv.w); l.w = bf16_rn(xv.w - bf16_tof(h.w));
        ((ushort4*)xh)[tid] = h;
        ((ushort4*)xl)[tid] = l;
    }
}

// k1: qkv = x @ W^T + b via 3-term bf16-split MFMA (hi*hi + hi*lo + lo*hi).
// grid = 3*(N/16) = 768 blocks x 256 threads (3 blocks/CU, full grid).
// q gets the 1/sqrt(32) scale folded in.
// C/D: col = lane&15, row = (lane>>4)*4 + reg  [m89-verified].
__global__ __launch_bounds__(256) void qkv_mfma_kernel(
    const u16* __restrict__ xh, const u16* __restrict__ xl,
    const u16* __restrict__ wH, const u16* __restrict__ wL,
    const float* __restrict__ bq, const float* __restrict__ bk, const float* __restrict__ bv,
    float* __restrict__ qo, float* __restrict__ ko, float* __restrict__ vo, int nrg)
{
    int bid = blockIdx.x;
    int s = bid / nrg;          // 0..2 (q/k/v)
    int rg = bid % nrg;
    int r0 = rg * 16;
    int w  = threadIdx.x >> 6;  // wave 0..3
    int l  = threadIdx.x & 63;
    int j0 = w * 32;
    int lr = l & 15;            // A-row / B-col / C-col within tile
    int kg = l >> 4;            // k-group (8 elems each)

    const u16* xhp = xh + (size_t)(r0 + lr) * C_DIM + kg * 8;
    const u16* xlp = xl + (size_t)(r0 + lr) * C_DIM + kg * 8;
    const u16* wh  = wH + (size_t)s * C_DIM * C_DIM;
    const u16* wl  = wL + (size_t)s * C_DIM * C_DIM;
    const u16* w0h = wh + (size_t)(j0 + lr) * C_DIM + kg * 8;
    const u16* w0l = wl + (size_t)(j0 + lr) * C_DIM + kg * 8;
    const u16* w1h = w0h + 16 * C_DIM;
    const u16* w1l = w0l + 16 * C_DIM;
    const float* B = (s == 0) ? bq : (s == 1) ? bk : bv;
    float*       O = (s == 0) ? qo : (s == 1) ? ko : vo;
    float fin = (s == 0) ? 0.17677669529663687f : 1.0f;   // fold q scale

    float b0 = B[j0 + lr], b1 = B[j0 + 16 + lr];
    f32x4 acc0 = {b0, b0, b0, b0};
    f32x4 acc1 = {b1, b1, b1, b1};

    #pragma unroll
    for (int kk = 0; kk < C_DIM; kk += 32) {
        short8 ah  = *(const short8*)(xhp + kk);
        short8 al  = *(const short8*)(xlp + kk);
        short8 bh0 = *(const short8*)(w0h + kk);
        short8 bl0 = *(const short8*)(w0l + kk);
        short8 bh1 = *(const short8*)(w1h + kk);
        short8 bl1 = *(const short8*)(w1l + kk);
        acc0 = __builtin_amdgcn_mfma_f32_16x16x32_bf16(ah, bh0, acc0, 0, 0, 0);
        acc0 = __builtin_amdgcn_mfma_f32_16x16x32_bf16(ah, bl0, acc0, 0, 0, 0);
        acc0 = __builtin_amdgcn_mfma_f32_16x16x32_bf16(al, bh0, acc0, 0, 0, 0);
        acc1 = __builtin_amdgcn_mfma_f32_16x16x32_bf16(ah, bh1, acc1, 0, 0, 0);
        acc1 = __builtin_amdgcn_mfma_f32_16x16x32_bf16(ah, bl1, acc1, 0, 0, 0);
        acc1 = __builtin_amdgcn_mfma_f32_16x16x32_bf16(al, bh1, acc1, 0, 0, 0);
    }
    size_t ob = (size_t)(r0 + kg * 4) * C_DIM;
    #pragma unroll
    for (int i = 0; i < 4; ++i) {
        O[ob + (size_t)i * C_DIM + j0 + lr]      = acc0[i] * fin;
        O[ob + (size_t)i * C_DIM + j0 + 16 + lr] = acc1[i] * fin;
    }
}

// k2: attention. wave = row, 8 rows/block, 512 blocks x 512 threads, ZERO
// barriers. Coalesced scoring: one neighbor per instruction, 64 lanes span the
// full 512B k-row (lane owns dims 2l,2l+1); dot finished via 4 shfl_xor within
// the 16-lane head-group; scores live in REGISTERS (slot j>>4, lane j&15 of
// each group) — no score LDS. cnt in SGPR -> all degree guards are uniform
// branches (tails skip loads). Output: ao * sinv as bf16 hi/lo split.
__global__ __launch_bounds__(512, 4) void attn_kernel(
    const float* __restrict__ q, const float* __restrict__ k,
    const float* __restrict__ v, const u64* __restrict__ bm, int wpr,
    u16* __restrict__ aoh, u16* __restrict__ aol)
{
    __shared__ int lm[8][64];         // per-wave neighbor list (cnt <= ~56)
    int t = threadIdx.x;
    int wave = t >> 6, lane = t & 63;
    int n = blockIdx.x * 8 + wave;    // this wave's row

    // ---- neighbor list from bitmap row (64 u64 words, one per lane) ----
    u64 bits = bm[(size_t)n * wpr + lane];
    int pc = __popcll(bits);
    int incl = pc;
    #pragma unroll
    for (int off = 1; off < 64; off <<= 1) {
        int tv = __shfl_up(incl, off);
        if (lane >= off) incl += tv;
    }
    int cnt = __builtin_amdgcn_readfirstlane(__shfl(incl, 63));  // wave-uniform SGPR
    int pos = incl - pc;
    u64 bb = bits;
    while (bb) {
        int b = __builtin_ctzll(bb);
        bb &= bb - 1;
        if (pos < 64) lm[wave][pos] = (lane << 6) + b;
        ++pos;
    }
    if (cnt > 64) cnt = 64;
    // (no barrier: lm is per-wave; DS ops are in-order within a wave)

    int g = lane >> 4;                // head of this lane's dims (2l,2l+1)
    float2 qf = *(const float2*)(q + (size_t)n * C_DIM + 2 * lane);  // scale pre-folded

    float sc0 = -1e30f, sc1 = -1e30f, sc2 = -1e30f, sc3 = -1e30f;
    float2 buf[32];                   // shared k-chunk / v-chunk staging

    // ---- scoring chunk 0 (j = 0..31) ----
    {
        int top = cnt < 32 ? cnt : 32;
        #pragma unroll
        for (int u = 0; u < 32; ++u)
            if (u < top)
                buf[u] = *(const float2*)(k + (size_t)lm[wave][u] * C_DIM + 2 * lane);
        #pragma unroll
        for (int u = 0; u < 32; ++u)
            if (u < top) {
                float s = qf.x * buf[u].x + qf.y * buf[u].y;
                s += __shfl_xor(s, 1); s += __shfl_xor(s, 2);
                s += __shfl_xor(s, 4); s += __shfl_xor(s, 8);
                if ((lane & 15) == (u & 15)) { if (u < 16) sc0 = s; else sc1 = s; }
            }
    }
    // ---- scoring chunk 1 (j = 32..63) ----
    if (cnt > 32) {
        #pragma unroll
        for (int u = 0; u < 32; ++u)
            if (32 + u < cnt)
                buf[u] = *(const float2*)(k + (size_t)lm[wave][32 + u] * C_DIM + 2 * lane);
        #pragma unroll
        for (int u = 0; u < 32; ++u)
            if (32 + u < cnt) {
                float s = qf.x * buf[u].x + qf.y * buf[u].y;
                s += __shfl_xor(s, 1); s += __shfl_xor(s, 2);
                s += __shfl_xor(s, 4); s += __shfl_xor(s, 8);
                if ((lane & 15) == (u & 15)) { if (u < 16) sc2 = s; else sc3 = s; }
            }
    }
    // ---- prefetch v chunk 0 (latency hides under softmax) ----
    {
        int top = cnt < 32 ? cnt : 32;
        #pragma unroll
        for (int u = 0; u < 32; ++u)
            if (u < top)
                buf[u] = *(const float2*)(v + (size_t)lm[wave][u] * C_DIM + 2 * lane);
    }
    // ---- softmax on register slots (16-lane group = head g) ----
    float mx = fmaxf(fmaxf(sc0, sc1), fmaxf(sc2, sc3));
    mx = fmaxf(mx, __shfl_xor(mx, 1)); mx = fmaxf(mx, __shfl_xor(mx, 2));
    mx = fmaxf(mx, __shfl_xor(mx, 4)); mx = fmaxf(mx, __shfl_xor(mx, 8));
    float e0 = __expf(sc0 - mx), e1 = __expf(sc1 - mx);
    float e2 = __expf(sc2 - mx), e3 = __expf(sc3 - mx);   // invalid slots -> exp(-inf)=0
    float sum = (e0 + e1) + (e2 + e3);
    sum += __shfl_xor(sum, 1); sum += __shfl_xor(sum, 2);
    sum += __shfl_xor(sum, 4); sum += __shfl_xor(sum, 8);
    float sinv = 1.0f / sum;          // >=1 neighbor (self-loop)

    // ---- PV chunk 0: e_j broadcast from lane (g<<4)|(j&15), slot j>>4 ----
    float2 acc = {0.f, 0.f};
    {
        int top = cnt < 32 ? cnt : 32;
        #pragma unroll
        for (int u = 0; u < 32; ++u)
            if (u < top) {
                float e = __shfl((u < 16) ? e0 : e1, (g << 4) | (u & 15));
                acc.x += e * buf[u].x;
                acc.y += e * buf[u].y;
            }
    }
    // ---- v chunk 1 + PV ----
    if (cnt > 32) {
        #pragma unroll
        for (int u = 0; u < 32; ++u)
            if (32 + u < cnt)
                buf[u] = *(const float2*)(v + (size_t)lm[wave][32 + u] * C_DIM + 2 * lane);
        #pragma unroll
        for (int u = 0; u < 32; ++u)
            if (32 + u < cnt) {
                float e = __shfl((u < 16) ? e2 : e3, (g << 4) | (u & 15));
                acc.x += e * buf[u].x;
                acc.y += e * buf[u].y;
            }
    }
    // ---- store ao as bf16 hi/lo split ----
    float f0 = acc.x * sinv, f1 = acc.y * sinv;
    ushort2 ho, lo;
    ho.x = bf16_rn(f0); lo.x = bf16_rn(f0 - bf16_tof(ho.x));
    ho.y = bf16_rn(f1); lo.y = bf16_rn(f1 - bf16_tof(ho.y));
    *(ushort2*)(aoh + (size_t)n * C_DIM + 2 * lane) = ho;
    *(ushort2*)(aol + (size_t)n * C_DIM + 2 * lane) = lo;
}

// k3: y = ao @ wo^T + bo + x, then LayerNorm. 16 real rows/block (full MFMA
// tile), 256 blocks x 256 threads; wo pre-split by prep.
__global__ __launch_bounds__(256) void oln_kernel(
    const u16* __restrict__ aoh, const u16* __restrict__ aol,
    const u16* __restrict__ woh, const u16* __restrict__ wol,
    const float* __restrict__ bo, const float* __restrict__ x,
    const float* __restrict__ gamma, const float* __restrict__ beta,
    float* __restrict__ out)
{
    __shared__ float ys[16 * 132];    // padded leading dim
    int r0 = blockIdx.x * 16;
    int w  = threadIdx.x >> 6;
    int l  = threadIdx.x & 63;
    int j0 = w * 32;
    int lr = l & 15;
    int kg = l >> 4;

    const u16* ahp = aoh + (size_t)(r0 + lr) * C_DIM + kg * 8;
    const u16* alp = aol + (size_t)(r0 + lr) * C_DIM + kg * 8;
    const u16* w0h = woh + (size_t)(j0 + lr) * C_DIM + kg * 8;
    const u16* w0l = wol + (size_t)(j0 + lr) * C_DIM + kg * 8;
    const u16* w1h = w0h + 16 * C_DIM;
    const u16* w1l = w0l + 16 * C_DIM;

    float b0 = bo[j0 + lr], b1 = bo[j0 + 16 + lr];
    f32x4 acc0 = {b0, b0, b0, b0};
    f32x4 acc1 = {b1, b1, b1, b1};

    #pragma unroll
    for (int kk = 0; kk < C_DIM; kk += 32) {
        short8 ah  = *(const short8*)(ahp + kk);
        short8 al  = *(const short8*)(alp + kk);
        short8 bh0 = *(const short8*)(w0h + kk);
        short8 bl0 = *(const short8*)(w0l + kk);
        short8 bh1 = *(const short8*)(w1h + kk);
        short8 bl1 = *(const short8*)(w1l + kk);
        acc0 = __builtin_amdgcn_mfma_f32_16x16x32_bf16(ah, bh0, acc0, 0, 0, 0);
        acc0 = __builtin_amdgcn_mfma_f32_16x16x32_bf16(ah, bl0, acc0, 0, 0, 0);
        acc0 = __builtin_amdgcn_mfma_f32_16x16x32_bf16(al, bh0, acc0, 0, 0, 0);
        acc1 = __builtin_amdgcn_mfma_f32_16x16x32_bf16(ah, bh1, acc1, 0, 0, 0);
        acc1 = __builtin_amdgcn_mfma_f32_16x16x32_bf16(ah, bl1, acc1, 0, 0, 0);
        acc1 = __builtin_amdgcn_mfma_f32_16x16x32_bf16(al, bh1, acc1, 0, 0, 0);
    }
    // ---- residual into LDS; rows kg*4+i (all 16 real) ----
    #pragma unroll
    for (int i = 0; i < 4; ++i) {
        int rr = kg * 4 + i;
        float y0 = acc0[i] + x[(size_t)(r0 + rr) * C_DIM + j0 + lr];
        float y1 = acc1[i] + x[(size_t)(r0 + rr) * C_DIM + j0 + 16 + lr];
        ys[rr * 132 + j0 + lr]      = y0;
        ys[rr * 132 + j0 + 16 + lr] = y1;
    }
    __syncthreads();
    // ---- LN: 16 threads per row, 8 cols each (256 threads = 16 rows) ----
    {
        int rr = threadIdx.x >> 4;
        int c0 = (threadIdx.x & 15) * 8;
        float yv[8];
        float s = 0.f, s2 = 0.f;
        #pragma unroll
        for (int u = 0; u < 8; ++u) {
            yv[u] = ys[rr * 132 + c0 + u];
            s += yv[u]; s2 += yv[u] * yv[u];
        }
        #pragma unroll
        for (int off = 8; off; off >>= 1) {
            s  += __shfl_xor(s, off);
            s2 += __shfl_xor(s2, off);
        }
        float mu = s * (1.0f / 128.0f);
        float var = s2 * (1.0f / 128.0f) - mu * mu;
        float rstd = rsqrtf(var + 1e-5f);
        size_t o = (size_t)(r0 + rr) * C_DIM + c0;
        #pragma unroll
        for (int u = 0; u < 8; ++u)
            out[o + u] = (yv[u] - mu) * rstd * gamma[c0 + u] + beta[c0 + u];
    }
}

extern "C" void kernel_launch(void* const* d_in, const int* in_sizes, int n_in,
                              void* d_out, int out_size, void* d_ws, size_t ws_size,
                              hipStream_t stream)
{
    const float* x     = (const float*)d_in[0];
    const int*   ei    = (const int*)d_in[1];
    const float* wq    = (const float*)d_in[2];
    const float* bq    = (const float*)d_in[3];
    const float* wk    = (const float*)d_in[4];
    const float* bk    = (const float*)d_in[5];
    const float* wv    = (const float*)d_in[6];
    const float* bv    = (const float*)d_in[7];
    const float* wo    = (const float*)d_in[8];
    const float* bo    = (const float*)d_in[9];
    const float* gamma = (const float*)d_in[10];
    const float* beta  = (const float*)d_in[11];
    float* out = (float*)d_out;

    int N = in_sizes[0] / C_DIM;   // 4096
    int E = in_sizes[1] / 2;       // 131072
    int wpr = N >> 6;              // u64 words per bitmap row (64)

    size_t MB = 1 << 20;
    char* base = (char*)d_ws;
    float* q   = (float*)(base + 0 * MB);            // 2 MiB
    float* k   = (float*)(base + 2 * MB);            // 2 MiB
    float* v   = (float*)(base + 4 * MB);            // 2 MiB
    u64*   bm  = (u64*)(base + 6 * MB);              // 2 MiB (N*N bits)
    u16*   xh  = (u16*)(base + 8 * MB);              // 1 MiB
    u16*   xl  = (u16*)(base + 9 * MB);              // 1 MiB
    u16*   wH  = (u16*)(base + 10 * MB);             // 128 KiB (q,k,v,o)
    u16*   wL  = (u16*)(base + 10 * MB + 256 * 1024);// 128 KiB
    u16*   aoh = (u16*)(base + 11 * MB);             // 1 MiB
    u16*   aol = (u16*)(base + 12 * MB);             // 1 MiB

    hipMemsetAsync(bm, 0, (size_t)N * wpr * sizeof(u64), stream);

    int xq = N * C_DIM / 4;                  // 131072 float4s
    prep_kernel<<<512, 256, 0, stream>>>(
        ei, E, bm, wpr, x, xh, xl, xq, wq, wk, wv, wo, wH, wL);

    int nrg = N / 16;                        // 256 row-groups
    qkv_mfma_kernel<<<3 * nrg, 256, 0, stream>>>(
        xh, xl, wH, wL, bq, bk, bv, q, k, v, nrg);

    attn_kernel<<<N / 8, 512, 0, stream>>>(q, k, v, bm, wpr, aoh, aol);

    oln_kernel<<<N / 16, 256, 0, stream>>>(
        aoh, aol, wH + 3 * C_DIM * C_DIM, wL + 3 * C_DIM * C_DIM,
        bo, x, gamma, beta, out);
}